// Round 1
// baseline (45.762 us; speedup 1.0000x reference)
//
#include <hip/hip_runtime.h>
#include <math.h>

#define KEXP 7
#define DDIM 1024
#define RDIM 128
#define TSEQ 2048
#define BBATCH 4
#define TAU_C 1.2f
#define EPS_C 1e-9f
#define LN_EPS_C 1e-5f

__device__ __forceinline__ float dot4(float4 a, float4 b) {
    return fmaf(a.x, b.x, fmaf(a.y, b.y, fmaf(a.z, b.z, a.w * b.w)));
}

// ---------------- K1: gate logits + softmax -> G (B*T rows) ----------------
// 1 wave per 4 rows; gate_w fragment register-staged (7 x 4 float4 per lane).
__global__ __launch_bounds__(256) void k_gate(const float* __restrict__ h,
                                              const float* __restrict__ gate_w,
                                              const float* __restrict__ gate_b,
                                              float* __restrict__ G) {
    const int lane = threadIdx.x & 63;
    const int wave = (blockIdx.x * blockDim.x + threadIdx.x) >> 6;
    const float4* gw4 = (const float4*)gate_w;
    float4 gw[KEXP][4];
#pragma unroll
    for (int k = 0; k < KEXP; ++k)
#pragma unroll
        for (int j = 0; j < 4; ++j)
            gw[k][j] = gw4[k * 256 + j * 64 + lane];
    float gb[KEXP];
#pragma unroll
    for (int k = 0; k < KEXP; ++k) gb[k] = gate_b[k];

    const int row0 = wave * 4;
#pragma unroll
    for (int r = 0; r < 4; ++r) {
        const int row = row0 + r;
        const float4* h4 = (const float4*)(h + (size_t)row * DDIM);
        float acc[KEXP];
#pragma unroll
        for (int k = 0; k < KEXP; ++k) acc[k] = 0.f;
#pragma unroll
        for (int j = 0; j < 4; ++j) {
            float4 hv = h4[j * 64 + lane];
#pragma unroll
            for (int k = 0; k < KEXP; ++k) {
                acc[k] = fmaf(hv.x, gw[k][j].x, acc[k]);
                acc[k] = fmaf(hv.y, gw[k][j].y, acc[k]);
                acc[k] = fmaf(hv.z, gw[k][j].z, acc[k]);
                acc[k] = fmaf(hv.w, gw[k][j].w, acc[k]);
            }
        }
#pragma unroll
        for (int k = 0; k < KEXP; ++k) {
#pragma unroll
            for (int off = 32; off > 0; off >>= 1)
                acc[k] += __shfl_xor(acc[k], off, 64);
        }
        float m = -1e30f;
#pragma unroll
        for (int k = 0; k < KEXP; ++k) { acc[k] += gb[k]; m = fmaxf(m, acc[k]); }
        float e[KEXP];
        float s = 0.f;
#pragma unroll
        for (int k = 0; k < KEXP; ++k) { e[k] = expf(acc[k] - m); s += e[k]; }
        const float inv = 1.f / s;
        if (lane == 0) {
#pragma unroll
            for (int k = 0; k < KEXP; ++k) G[row * KEXP + k] = e[k] * inv;
        }
    }
}

// ------- K2: per (batch, expert) last-token states + layernorm -> y -------
// grid = B*K blocks, 256 threads. Each block: recompute basis (h_row @ U_w^T),
// leftover weights from G, then s_d = sum_r basis_r * V[k,r,d], LN stats,
// write y[b][k][d] = w_k * (s_d - mu) * rsqrt(var+eps).
__global__ __launch_bounds__(256) void k_states(const float* __restrict__ h,
                                                const float* __restrict__ U_w,
                                                const float* __restrict__ V,
                                                const float* __restrict__ G,
                                                float* __restrict__ y,
                                                float* __restrict__ wws) {
    const int b = blockIdx.x / KEXP;
    const int k = blockIdx.x % KEXP;
    const int tid = threadIdx.x;
    const int lane = tid & 63;
    const int wv = tid >> 6;

    __shared__ float basis[RDIM];
    __shared__ float wsh[8];
    __shared__ float r1[4], r2[4];

    const int row = b * TSEQ + (TSEQ - 1);

    if (tid == 0) {
        float g[KEXP];
#pragma unroll
        for (int j = 0; j < KEXP; ++j) g[j] = G[row * KEXP + j];
        int i1 = 0;
        for (int j = 1; j < KEXP; ++j) if (g[j] > g[i1]) i1 = j;
        int i2 = -1;
        for (int j = 0; j < KEXP; ++j)
            if (j != i1 && (i2 < 0 || g[j] > g[i2])) i2 = j;
        int i3 = -1;
        for (int j = 0; j < KEXP; ++j)
            if (j != i1 && j != i2 && (i3 < 0 || g[j] > g[i3])) i3 = j;
        int i4 = -1;
        for (int j = 0; j < KEXP; ++j)
            if (j != i1 && j != i2 && j != i3 && (i4 < 0 || g[j] > g[i4])) i4 = j;
        float s = fmaxf(g[i3] + g[i4], EPS_C);
        float p[KEXP];
#pragma unroll
        for (int j = 0; j < KEXP; ++j) p[j] = 0.f;
        p[i3] = g[i3] / s;
        p[i4] = g[i4] / s;
        float l[KEXP], m = -1e30f;
#pragma unroll
        for (int j = 0; j < KEXP; ++j) {
            l[j] = logf(fmaxf(p[j], EPS_C)) * (1.f / TAU_C);
            m = fmaxf(m, l[j]);
        }
        float es = 0.f, w[KEXP];
#pragma unroll
        for (int j = 0; j < KEXP; ++j) { w[j] = expf(l[j] - m); es += w[j]; }
        const float inv = 1.f / es;
        float wsum = 0.f;
#pragma unroll
        for (int j = 0; j < KEXP; ++j) { w[j] *= inv; wsum += w[j]; wsh[j] = w[j]; }
        wsh[7] = wsum;
        if (k == 0) {
#pragma unroll
            for (int j = 0; j < KEXP; ++j) wws[b * 8 + j] = w[j];
            wws[b * 8 + 7] = wsum;
        }
    }

    // basis: 4 waves x 32 r each
    const float4* h4 = (const float4*)(h + (size_t)row * DDIM);
    float4 hf[4];
#pragma unroll
    for (int j = 0; j < 4; ++j) hf[j] = h4[j * 64 + lane];
    for (int rr = 0; rr < 32; ++rr) {
        const int r = wv * 32 + rr;
        const float4* u4 = (const float4*)(U_w + (size_t)r * DDIM);
        float a = 0.f;
#pragma unroll
        for (int j = 0; j < 4; ++j) a += dot4(hf[j], u4[j * 64 + lane]);
#pragma unroll
        for (int off = 32; off > 0; off >>= 1) a += __shfl_xor(a, off, 64);
        if (lane == 0) basis[r] = a;
    }
    __syncthreads();

    // s_d for d = 4*tid .. 4*tid+3
    const float4* V4 = (const float4*)(V + (size_t)k * RDIM * DDIM);
    float4 acc = {0.f, 0.f, 0.f, 0.f};
#pragma unroll 8
    for (int r = 0; r < RDIM; ++r) {
        float4 v = V4[r * 256 + tid];
        const float br = basis[r];
        acc.x = fmaf(br, v.x, acc.x);
        acc.y = fmaf(br, v.y, acc.y);
        acc.z = fmaf(br, v.z, acc.z);
        acc.w = fmaf(br, v.w, acc.w);
    }
    float p1 = acc.x + acc.y + acc.z + acc.w;
    float p2 = acc.x * acc.x + acc.y * acc.y + acc.z * acc.z + acc.w * acc.w;
#pragma unroll
    for (int off = 32; off > 0; off >>= 1) {
        p1 += __shfl_xor(p1, off, 64);
        p2 += __shfl_xor(p2, off, 64);
    }
    if (lane == 0) { r1[wv] = p1; r2[wv] = p2; }
    __syncthreads();
    const float t1 = r1[0] + r1[1] + r1[2] + r1[3];
    const float t2 = r2[0] + r2[1] + r2[2] + r2[3];
    const float mu = t1 * (1.f / (float)DDIM);
    const float var = t2 * (1.f / (float)DDIM) - mu * mu;
    const float rs = rsqrtf(var + LN_EPS_C);
    const float wk = wsh[k];
    float4 yv;
    yv.x = wk * (acc.x - mu) * rs;
    yv.y = wk * (acc.y - mu) * rs;
    yv.z = wk * (acc.z - mu) * rs;
    yv.w = wk * (acc.w - mu) * rs;
    ((float4*)y)[(b * KEXP + k) * 256 + tid] = yv;
}

// ------------- K3: bvec[b][d] = ln_g*sum_k y + ln_b*wsum -------------
__global__ __launch_bounds__(256) void k_bvec(const float* __restrict__ y,
                                              const float* __restrict__ wws,
                                              const float* __restrict__ ln_g,
                                              const float* __restrict__ ln_b,
                                              float* __restrict__ bvec) {
    const int b = blockIdx.x;
    const int tid = threadIdx.x;
    const float wsum = wws[b * 8 + 7];
    float4 s = {0.f, 0.f, 0.f, 0.f};
#pragma unroll
    for (int k = 0; k < KEXP; ++k) {
        float4 v = ((const float4*)y)[(b * KEXP + k) * 256 + tid];
        s.x += v.x; s.y += v.y; s.z += v.z; s.w += v.w;
    }
    float4 g = ((const float4*)ln_g)[tid];
    float4 bb = ((const float4*)ln_b)[tid];
    float4 o;
    o.x = g.x * s.x + bb.x * wsum;
    o.y = g.y * s.y + bb.y * wsum;
    o.z = g.z * s.z + bb.z * wsum;
    o.w = g.w * s.w + bb.w * wsum;
    ((float4*)bvec)[b * 256 + tid] = o;
}

// ------------- K4: out[b][e] = bvec[b] . comp_w[e] + comp_b[e] -------------
// 1 wave per e; 1024 waves = 256 blocks x 4 waves.
__global__ __launch_bounds__(256) void k_comp(const float* __restrict__ bvec,
                                              const float* __restrict__ comp_w,
                                              const float* __restrict__ comp_b,
                                              float* __restrict__ out) {
    const int lane = threadIdx.x & 63;
    const int e = (blockIdx.x * blockDim.x + threadIdx.x) >> 6;
    const float4* cw4 = (const float4*)(comp_w + (size_t)e * DDIM);
    float4 bv[BBATCH][4];
#pragma unroll
    for (int row = 0; row < BBATCH; ++row)
#pragma unroll
        for (int j = 0; j < 4; ++j)
            bv[row][j] = ((const float4*)bvec)[row * 256 + j * 64 + lane];
    float acc[BBATCH] = {0.f, 0.f, 0.f, 0.f};
#pragma unroll
    for (int j = 0; j < 4; ++j) {
        float4 c = cw4[j * 64 + lane];
#pragma unroll
        for (int row = 0; row < BBATCH; ++row) acc[row] += dot4(c, bv[row][j]);
    }
#pragma unroll
    for (int row = 0; row < BBATCH; ++row)
#pragma unroll
        for (int off = 32; off > 0; off >>= 1)
            acc[row] += __shfl_xor(acc[row], off, 64);
    if (lane == 0) {
        const float cb = comp_b[e];
#pragma unroll
        for (int row = 0; row < BBATCH; ++row)
            out[row * DDIM + e] = acc[row] + cb;
    }
}

extern "C" void kernel_launch(void* const* d_in, const int* in_sizes, int n_in,
                              void* d_out, int out_size, void* d_ws, size_t ws_size,
                              hipStream_t stream) {
    const float* h      = (const float*)d_in[0];
    const float* gate_w = (const float*)d_in[1];
    const float* gate_b = (const float*)d_in[2];
    const float* U_w    = (const float*)d_in[3];
    const float* V      = (const float*)d_in[4];
    const float* ln_g   = (const float*)d_in[5];
    const float* ln_b   = (const float*)d_in[6];
    const float* comp_w = (const float*)d_in[7];
    const float* comp_b = (const float*)d_in[8];

    float* out = (float*)d_out;                 // b: 4*1024 floats
    float* G   = out + BBATCH * DDIM;           // G: 4*2048*7 floats

    float* ws   = (float*)d_ws;
    float* y    = ws;                           // 4*7*1024
    float* wws  = y + BBATCH * KEXP * DDIM;     // 4*8
    float* bvec = wws + BBATCH * 8;             // 4*1024

    // B*T = 8192 rows, 4 rows/wave, 4 waves/block -> 512 blocks
    k_gate<<<512, 256, 0, stream>>>(h, gate_w, gate_b, G);
    k_states<<<BBATCH * KEXP, 256, 0, stream>>>(h, U_w, V, G, y, wws);
    k_bvec<<<BBATCH, 256, 0, stream>>>(y, wws, ln_g, ln_b, bvec);
    k_comp<<<256, 256, 0, stream>>>(bvec, comp_w, comp_b, out);
}

// Round 2
// 33.493 us; speedup vs baseline: 1.3663x; 1.3663x over previous
//
#include <hip/hip_runtime.h>
#include <math.h>

#define KEXP 7
#define DDIM 1024
#define RDIM 128
#define TSEQ 2048
#define BBATCH 4
#define TAU_C 1.2f
#define EPS_C 1e-9f
#define LN_EPS_C 1e-5f

__device__ __forceinline__ float dot4(float4 a, float4 b) {
    return fmaf(a.x, b.x, fmaf(a.y, b.y, fmaf(a.z, b.z, a.w * b.w)));
}

// ---------------- K1: gate logits + softmax -> G (B*T rows) ----------------
// 1 wave per 4 rows; gate_w fragment register-staged (7 x 4 float4 per lane).
__global__ __launch_bounds__(256) void k_gate(const float* __restrict__ h,
                                              const float* __restrict__ gate_w,
                                              const float* __restrict__ gate_b,
                                              float* __restrict__ G) {
    const int lane = threadIdx.x & 63;
    const int wave = (blockIdx.x * blockDim.x + threadIdx.x) >> 6;
    const float4* gw4 = (const float4*)gate_w;
    float4 gw[KEXP][4];
#pragma unroll
    for (int k = 0; k < KEXP; ++k)
#pragma unroll
        for (int j = 0; j < 4; ++j)
            gw[k][j] = gw4[k * 256 + j * 64 + lane];
    float gb[KEXP];
#pragma unroll
    for (int k = 0; k < KEXP; ++k) gb[k] = gate_b[k];

    const int row0 = wave * 4;
#pragma unroll
    for (int r = 0; r < 4; ++r) {
        const int row = row0 + r;
        const float4* h4 = (const float4*)(h + (size_t)row * DDIM);
        float acc[KEXP];
#pragma unroll
        for (int k = 0; k < KEXP; ++k) acc[k] = 0.f;
#pragma unroll
        for (int j = 0; j < 4; ++j) {
            float4 hv = h4[j * 64 + lane];
#pragma unroll
            for (int k = 0; k < KEXP; ++k) {
                acc[k] = fmaf(hv.x, gw[k][j].x, acc[k]);
                acc[k] = fmaf(hv.y, gw[k][j].y, acc[k]);
                acc[k] = fmaf(hv.z, gw[k][j].z, acc[k]);
                acc[k] = fmaf(hv.w, gw[k][j].w, acc[k]);
            }
        }
#pragma unroll
        for (int k = 0; k < KEXP; ++k) {
#pragma unroll
            for (int off = 32; off > 0; off >>= 1)
                acc[k] += __shfl_xor(acc[k], off, 64);
        }
        float m = -1e30f;
#pragma unroll
        for (int k = 0; k < KEXP; ++k) { acc[k] += gb[k]; m = fmaxf(m, acc[k]); }
        float e[KEXP];
        float s = 0.f;
#pragma unroll
        for (int k = 0; k < KEXP; ++k) { e[k] = expf(acc[k] - m); s += e[k]; }
        const float inv = 1.f / s;
        if (lane == 0) {
#pragma unroll
            for (int k = 0; k < KEXP; ++k) G[row * KEXP + k] = e[k] * inv;
        }
    }
}

// ------- K2: per (batch, expert) last-token states + layernorm -> y -------
// grid = B*K blocks, 1024 threads (16 waves -> real latency hiding).
// Self-contained: recomputes the last-token gate row (no dep on k_gate).
// y[b][k][d] = w_k * (s_d - mu) * rsqrt(var+eps);  wws[b*8+7] = wsum.
__global__ __launch_bounds__(1024) void k_states(const float* __restrict__ h,
                                                 const float* __restrict__ gate_w,
                                                 const float* __restrict__ gate_b,
                                                 const float* __restrict__ U_w,
                                                 const float* __restrict__ V,
                                                 float* __restrict__ y,
                                                 float* __restrict__ wws) {
    const int b = blockIdx.x / KEXP;
    const int k = blockIdx.x % KEXP;
    const int tid = threadIdx.x;
    const int lane = tid & 63;
    const int wv = tid >> 6;         // 0..15

    __shared__ float basis[RDIM];
    __shared__ float logits[KEXP];
    __shared__ float wsh[8];
    __shared__ float4 part4[4][256];
    __shared__ float red1[4], red2[4];

    const float* hrow = h + ((size_t)b * TSEQ + (TSEQ - 1)) * DDIM;
    const float4* h4 = (const float4*)hrow;

    // ---- phase 0: gate logits for last token (waves 0..6, one expert each)
    if (wv < KEXP) {
        const float4* gw4 = (const float4*)(gate_w + (size_t)wv * DDIM);
        float a = 0.f;
#pragma unroll
        for (int j = 0; j < 4; ++j) a += dot4(h4[j * 64 + lane], gw4[j * 64 + lane]);
#pragma unroll
        for (int off = 32; off > 0; off >>= 1) a += __shfl_xor(a, off, 64);
        if (lane == 0) logits[wv] = a + gate_b[wv];
    }
    __syncthreads();

    // ---- serial leftover-weight computation on tid 0 (7 elements)
    if (tid == 0) {
        float l0[KEXP], m0 = -1e30f;
#pragma unroll
        for (int j = 0; j < KEXP; ++j) { l0[j] = logits[j]; m0 = fmaxf(m0, l0[j]); }
        float es0 = 0.f, g[KEXP];
#pragma unroll
        for (int j = 0; j < KEXP; ++j) { g[j] = expf(l0[j] - m0); es0 += g[j]; }
        const float inv0 = 1.f / es0;
#pragma unroll
        for (int j = 0; j < KEXP; ++j) g[j] *= inv0;
        int i1 = 0;
        for (int j = 1; j < KEXP; ++j) if (g[j] > g[i1]) i1 = j;
        int i2 = -1;
        for (int j = 0; j < KEXP; ++j)
            if (j != i1 && (i2 < 0 || g[j] > g[i2])) i2 = j;
        int i3 = -1;
        for (int j = 0; j < KEXP; ++j)
            if (j != i1 && j != i2 && (i3 < 0 || g[j] > g[i3])) i3 = j;
        int i4 = -1;
        for (int j = 0; j < KEXP; ++j)
            if (j != i1 && j != i2 && j != i3 && (i4 < 0 || g[j] > g[i4])) i4 = j;
        float s = fmaxf(g[i3] + g[i4], EPS_C);
        float p[KEXP];
#pragma unroll
        for (int j = 0; j < KEXP; ++j) p[j] = 0.f;
        p[i3] = g[i3] / s;
        p[i4] = g[i4] / s;
        float l[KEXP], m = -1e30f;
#pragma unroll
        for (int j = 0; j < KEXP; ++j) {
            l[j] = logf(fmaxf(p[j], EPS_C)) * (1.f / TAU_C);
            m = fmaxf(m, l[j]);
        }
        float es = 0.f, w[KEXP];
#pragma unroll
        for (int j = 0; j < KEXP; ++j) { w[j] = expf(l[j] - m); es += w[j]; }
        const float inv = 1.f / es;
        float wsum = 0.f;
#pragma unroll
        for (int j = 0; j < KEXP; ++j) { w[j] *= inv; wsum += w[j]; wsh[j] = w[j]; }
        wsh[7] = wsum;
        if (k == 0) {
#pragma unroll
            for (int j = 0; j < KEXP; ++j) wws[b * 8 + j] = w[j];
            wws[b * 8 + 7] = wsum;
        }
    }

    // ---- phase 1: basis[r] = hrow . U_w[r]; wave wv owns r = 8*wv..8*wv+7.
    {
        float4 hf[4];
#pragma unroll
        for (int j = 0; j < 4; ++j) hf[j] = h4[j * 64 + lane];
        const int r0 = wv * 8;
        float part[8];
#pragma unroll
        for (int rr = 0; rr < 8; ++rr) {
            const float4* u4 = (const float4*)(U_w + (size_t)(r0 + rr) * DDIM);
            float a = 0.f;
#pragma unroll
            for (int j = 0; j < 4; ++j) a += dot4(hf[j], u4[j * 64 + lane]);
            part[rr] = a;
        }
        // 8 independent reduce chains -> ILP hides ds latency
#pragma unroll
        for (int off = 32; off > 0; off >>= 1)
#pragma unroll
            for (int rr = 0; rr < 8; ++rr)
                part[rr] += __shfl_xor(part[rr], off, 64);
        if (lane == 0) {
#pragma unroll
            for (int rr = 0; rr < 8; ++rr) basis[r0 + rr] = part[rr];
        }
    }
    __syncthreads();

    // ---- phase 2: partial s_d over r-quarter. g = tid>>8, c = tid&255.
    {
        const int gq = tid >> 8;
        const int c = tid & 255;
        const float4* V4 = (const float4*)(V + (size_t)k * RDIM * DDIM);
        float4 acc = {0.f, 0.f, 0.f, 0.f};
#pragma unroll 8
        for (int r8 = 0; r8 < 32; ++r8) {
            const int r = gq * 32 + r8;
            float4 v = V4[(size_t)r * 256 + c];
            const float br = basis[r];
            acc.x = fmaf(br, v.x, acc.x);
            acc.y = fmaf(br, v.y, acc.y);
            acc.z = fmaf(br, v.z, acc.z);
            acc.w = fmaf(br, v.w, acc.w);
        }
        part4[gq][c] = acc;
    }
    __syncthreads();

    // ---- phase 3: combine partials, LN stats, write y (threads 0..255)
    float4 s4 = {0.f, 0.f, 0.f, 0.f};
    float p1 = 0.f, p2 = 0.f;
    if (tid < 256) {
        float4 a0 = part4[0][tid], a1 = part4[1][tid], a2 = part4[2][tid], a3 = part4[3][tid];
        s4.x = a0.x + a1.x + a2.x + a3.x;
        s4.y = a0.y + a1.y + a2.y + a3.y;
        s4.z = a0.z + a1.z + a2.z + a3.z;
        s4.w = a0.w + a1.w + a2.w + a3.w;
        p1 = s4.x + s4.y + s4.z + s4.w;
        p2 = s4.x * s4.x + s4.y * s4.y + s4.z * s4.z + s4.w * s4.w;
#pragma unroll
        for (int off = 32; off > 0; off >>= 1) {
            p1 += __shfl_xor(p1, off, 64);
            p2 += __shfl_xor(p2, off, 64);
        }
        if (lane == 0) { red1[tid >> 6] = p1; red2[tid >> 6] = p2; }
    }
    __syncthreads();
    if (tid < 256) {
        const float t1 = red1[0] + red1[1] + red1[2] + red1[3];
        const float t2 = red2[0] + red2[1] + red2[2] + red2[3];
        const float mu = t1 * (1.f / (float)DDIM);
        const float var = t2 * (1.f / (float)DDIM) - mu * mu;
        const float rs = rsqrtf(var + LN_EPS_C);
        const float wk = wsh[k];
        float4 yv;
        yv.x = wk * (s4.x - mu) * rs;
        yv.y = wk * (s4.y - mu) * rs;
        yv.z = wk * (s4.z - mu) * rs;
        yv.w = wk * (s4.w - mu) * rs;
        ((float4*)y)[(size_t)(b * KEXP + k) * 256 + tid] = yv;
    }
}

// ------- K3: fused bvec rebuild (LDS) + out[b][e] = bvec[b].comp_w[e]+comp_b[e]
// 256 blocks x 256 threads; block handles 4 e's (one per wave).
__global__ __launch_bounds__(256) void k_comp(const float* __restrict__ y,
                                              const float* __restrict__ wws,
                                              const float* __restrict__ ln_g,
                                              const float* __restrict__ ln_b,
                                              const float* __restrict__ comp_w,
                                              const float* __restrict__ comp_b,
                                              float* __restrict__ out) {
    const int tid = threadIdx.x;
    const int lane = tid & 63;
    const int wv = tid >> 6;

    __shared__ float4 bv[BBATCH][256];

    // rebuild bvec: thread c handles float4 column c for all 4 batches
    {
        const float4* y4 = (const float4*)y;
        const float4 g4 = ((const float4*)ln_g)[tid];
        const float4 b4 = ((const float4*)ln_b)[tid];
#pragma unroll
        for (int b = 0; b < BBATCH; ++b) {
            float4 s = {0.f, 0.f, 0.f, 0.f};
#pragma unroll
            for (int k = 0; k < KEXP; ++k) {
                float4 v = y4[(size_t)(b * KEXP + k) * 256 + tid];
                s.x += v.x; s.y += v.y; s.z += v.z; s.w += v.w;
            }
            const float wsum = wws[b * 8 + 7];
            float4 o;
            o.x = g4.x * s.x + b4.x * wsum;
            o.y = g4.y * s.y + b4.y * wsum;
            o.z = g4.z * s.z + b4.z * wsum;
            o.w = g4.w * s.w + b4.w * wsum;
            bv[b][tid] = o;
        }
    }
    __syncthreads();

    const int e = blockIdx.x * 4 + wv;
    const float4* cw4 = (const float4*)(comp_w + (size_t)e * DDIM);
    float acc[BBATCH] = {0.f, 0.f, 0.f, 0.f};
#pragma unroll
    for (int j = 0; j < 4; ++j) {
        float4 c = cw4[j * 64 + lane];
#pragma unroll
        for (int b = 0; b < BBATCH; ++b) acc[b] += dot4(c, bv[b][j * 64 + lane]);
    }
#pragma unroll
    for (int b = 0; b < BBATCH; ++b)
#pragma unroll
        for (int off = 32; off > 0; off >>= 1)
            acc[b] += __shfl_xor(acc[b], off, 64);
    if (lane == 0) {
        const float cb = comp_b[e];
#pragma unroll
        for (int b = 0; b < BBATCH; ++b)
            out[b * DDIM + e] = acc[b] + cb;
    }
}

extern "C" void kernel_launch(void* const* d_in, const int* in_sizes, int n_in,
                              void* d_out, int out_size, void* d_ws, size_t ws_size,
                              hipStream_t stream) {
    const float* h      = (const float*)d_in[0];
    const float* gate_w = (const float*)d_in[1];
    const float* gate_b = (const float*)d_in[2];
    const float* U_w    = (const float*)d_in[3];
    const float* V      = (const float*)d_in[4];
    const float* ln_g   = (const float*)d_in[5];
    const float* ln_b   = (const float*)d_in[6];
    const float* comp_w = (const float*)d_in[7];
    const float* comp_b = (const float*)d_in[8];

    float* out = (float*)d_out;                 // b: 4*1024 floats
    float* G   = out + BBATCH * DDIM;           // G: 4*2048*7 floats

    float* ws   = (float*)d_ws;
    float* y    = ws;                           // 4*7*1024
    float* wws  = y + BBATCH * KEXP * DDIM;     // 4*8

    k_states<<<BBATCH * KEXP, 1024, 0, stream>>>(h, gate_w, gate_b, U_w, V, y, wws);
    k_gate<<<512, 256, 0, stream>>>(h, gate_w, gate_b, G);
    k_comp<<<256, 256, 0, stream>>>(y, wws, ln_g, ln_b, comp_w, comp_b, out);
}

// Round 3
// 23.352 us; speedup vs baseline: 1.9597x; 1.4343x over previous
//
#include <hip/hip_runtime.h>
#include <math.h>

#define KEXP 7
#define DDIM 1024
#define RDIM 128
#define TSEQ 2048
#define BBATCH 4
#define TAU_C 1.2f
#define EPS_C 1e-9f
#define LN_EPS_C 1e-5f

// ws float offsets
#define WS_S     0        // s[b][k][1024]            : 28672 floats
#define WS_BASIS 28672    // basis[b][128]            : 512
#define WS_W     29184    // w[b][8] (7 w + wsum)     : 32
#define WS_PSTAT 29216    // pstats[b][k][16][2]      : 896

__device__ __forceinline__ float dot4(float4 a, float4 b) {
    return fmaf(a.x, b.x, fmaf(a.y, b.y, fmaf(a.z, b.z, a.w * b.w)));
}

// ---- K1: gate softmax over all rows (blocks 0..511)
//      + basis blocks (512..543): basis[b][r] = h_last . U_w[r]
//      + weight blocks (544..547): leftover weights per batch
__global__ __launch_bounds__(256) void k_gate_plus(const float* __restrict__ h,
                                                   const float* __restrict__ gate_w,
                                                   const float* __restrict__ gate_b,
                                                   const float* __restrict__ U_w,
                                                   float* __restrict__ G,
                                                   float* __restrict__ ws) {
    const int bid = blockIdx.x;
    const int tid = threadIdx.x;
    const int lane = tid & 63;
    const int wv = tid >> 6;
    __shared__ float sh_logits[8];

    if (bid < 512) {
        // ---------------- gate role ----------------
        const float4* gw4 = (const float4*)gate_w;
        float4 gw[KEXP][4];
#pragma unroll
        for (int k = 0; k < KEXP; ++k)
#pragma unroll
            for (int j = 0; j < 4; ++j)
                gw[k][j] = gw4[k * 256 + j * 64 + lane];
        float gb[KEXP];
#pragma unroll
        for (int k = 0; k < KEXP; ++k) gb[k] = gate_b[k];

        const int row0 = (bid * 4 + wv) * 4;
#pragma unroll
        for (int r = 0; r < 4; ++r) {
            const int row = row0 + r;
            const float4* h4 = (const float4*)(h + (size_t)row * DDIM);
            float acc[KEXP];
#pragma unroll
            for (int k = 0; k < KEXP; ++k) acc[k] = 0.f;
#pragma unroll
            for (int j = 0; j < 4; ++j) {
                float4 hv = h4[j * 64 + lane];
#pragma unroll
                for (int k = 0; k < KEXP; ++k) {
                    acc[k] = fmaf(hv.x, gw[k][j].x, acc[k]);
                    acc[k] = fmaf(hv.y, gw[k][j].y, acc[k]);
                    acc[k] = fmaf(hv.z, gw[k][j].z, acc[k]);
                    acc[k] = fmaf(hv.w, gw[k][j].w, acc[k]);
                }
            }
#pragma unroll
            for (int k = 0; k < KEXP; ++k) {
#pragma unroll
                for (int off = 32; off > 0; off >>= 1)
                    acc[k] += __shfl_xor(acc[k], off, 64);
            }
            float m = -1e30f;
#pragma unroll
            for (int k = 0; k < KEXP; ++k) { acc[k] += gb[k]; m = fmaxf(m, acc[k]); }
            float e[KEXP];
            float s = 0.f;
#pragma unroll
            for (int k = 0; k < KEXP; ++k) { e[k] = expf(acc[k] - m); s += e[k]; }
            const float inv = 1.f / s;
            if (lane == 0) {
#pragma unroll
                for (int k = 0; k < KEXP; ++k) G[row * KEXP + k] = e[k] * inv;
            }
        }
    } else if (bid < 544) {
        // ---------------- basis role ----------------
        const int idx = bid - 512;
        const int b = idx >> 3;
        const int chunk = idx & 7;   // 16 r's
        const float4* h4 = (const float4*)(h + ((size_t)b * TSEQ + (TSEQ - 1)) * DDIM);
        float4 hf[4];
#pragma unroll
        for (int j = 0; j < 4; ++j) hf[j] = h4[j * 64 + lane];
        const int r0 = chunk * 16 + wv * 4;
        float part[4];
#pragma unroll
        for (int rr = 0; rr < 4; ++rr) {
            const float4* u4 = (const float4*)(U_w + (size_t)(r0 + rr) * DDIM);
            float a = 0.f;
#pragma unroll
            for (int j = 0; j < 4; ++j) a += dot4(hf[j], u4[j * 64 + lane]);
            part[rr] = a;
        }
#pragma unroll
        for (int off = 32; off > 0; off >>= 1)
#pragma unroll
            for (int rr = 0; rr < 4; ++rr)
                part[rr] += __shfl_xor(part[rr], off, 64);
        if (lane == 0) {
#pragma unroll
            for (int rr = 0; rr < 4; ++rr)
                ws[WS_BASIS + b * RDIM + r0 + rr] = part[rr];
        }
    } else {
        // ---------------- weights role ----------------
        const int b = bid - 544;
        const float4* h4 = (const float4*)(h + ((size_t)b * TSEQ + (TSEQ - 1)) * DDIM);
        for (int e = wv; e < KEXP; e += 4) {
            const float4* gw4 = (const float4*)(gate_w + (size_t)e * DDIM);
            float a = 0.f;
#pragma unroll
            for (int j = 0; j < 4; ++j) a += dot4(h4[j * 64 + lane], gw4[j * 64 + lane]);
#pragma unroll
            for (int off = 32; off > 0; off >>= 1) a += __shfl_xor(a, off, 64);
            if (lane == 0) sh_logits[e] = a + gate_b[e];
        }
        __syncthreads();
        if (tid == 0) {
            float l0[KEXP], m0 = -1e30f;
#pragma unroll
            for (int j = 0; j < KEXP; ++j) { l0[j] = sh_logits[j]; m0 = fmaxf(m0, l0[j]); }
            float es0 = 0.f, g[KEXP];
#pragma unroll
            for (int j = 0; j < KEXP; ++j) { g[j] = expf(l0[j] - m0); es0 += g[j]; }
            const float inv0 = 1.f / es0;
#pragma unroll
            for (int j = 0; j < KEXP; ++j) g[j] *= inv0;
            int i1 = 0;
            for (int j = 1; j < KEXP; ++j) if (g[j] > g[i1]) i1 = j;
            int i2 = -1;
            for (int j = 0; j < KEXP; ++j)
                if (j != i1 && (i2 < 0 || g[j] > g[i2])) i2 = j;
            int i3 = -1;
            for (int j = 0; j < KEXP; ++j)
                if (j != i1 && j != i2 && (i3 < 0 || g[j] > g[i3])) i3 = j;
            int i4 = -1;
            for (int j = 0; j < KEXP; ++j)
                if (j != i1 && j != i2 && j != i3 && (i4 < 0 || g[j] > g[i4])) i4 = j;
            float s = fmaxf(g[i3] + g[i4], EPS_C);
            float p[KEXP];
#pragma unroll
            for (int j = 0; j < KEXP; ++j) p[j] = 0.f;
            p[i3] = g[i3] / s;
            p[i4] = g[i4] / s;
            float l[KEXP], m = -1e30f;
#pragma unroll
            for (int j = 0; j < KEXP; ++j) {
                l[j] = logf(fmaxf(p[j], EPS_C)) * (1.f / TAU_C);
                m = fmaxf(m, l[j]);
            }
            float es = 0.f, w[KEXP];
#pragma unroll
            for (int j = 0; j < KEXP; ++j) { w[j] = expf(l[j] - m); es += w[j]; }
            const float inv = 1.f / es;
            float wsum = 0.f;
#pragma unroll
            for (int j = 0; j < KEXP; ++j) { w[j] *= inv; wsum += w[j]; ws[WS_W + b * 8 + j] = w[j]; }
            ws[WS_W + b * 8 + 7] = wsum;
        }
    }
}

// ---- K2: s[b][k][d] = sum_r basis[b][r] * V[k][r][d], V streamed once.
// grid = K*16 blocks; block handles (k, 64-d chunk) for ALL batches.
// Also writes per-chunk partial LN stats (sum, sumsq) per (b,k).
__global__ __launch_bounds__(256) void k_sv(const float* __restrict__ V,
                                            float* __restrict__ ws) {
    const int k = blockIdx.x >> 4;
    const int chunk = blockIdx.x & 15;    // 64 d's = 16 float4
    const int tid = threadIdx.x;
    const int col = tid & 15;             // float4 col in chunk
    const int rc = tid >> 4;              // 0..15 (8 r's each)

    __shared__ float basis_sh[BBATCH * RDIM];
    __shared__ float4 part[16][BBATCH][16];   // [rc][b][col]

    basis_sh[tid] = ws[WS_BASIS + tid];
    basis_sh[tid + 256] = ws[WS_BASIS + tid + 256];
    __syncthreads();

    const float4* V4 = (const float4*)(V + (size_t)k * RDIM * DDIM);
    float4 acc[BBATCH];
#pragma unroll
    for (int b = 0; b < BBATCH; ++b) acc[b] = make_float4(0.f, 0.f, 0.f, 0.f);
#pragma unroll
    for (int rr = 0; rr < 8; ++rr) {
        const int r = rc * 8 + rr;
        float4 v = V4[(size_t)r * 256 + chunk * 16 + col];
#pragma unroll
        for (int b = 0; b < BBATCH; ++b) {
            const float br = basis_sh[b * RDIM + r];
            acc[b].x = fmaf(br, v.x, acc[b].x);
            acc[b].y = fmaf(br, v.y, acc[b].y);
            acc[b].z = fmaf(br, v.z, acc[b].z);
            acc[b].w = fmaf(br, v.w, acc[b].w);
        }
    }
#pragma unroll
    for (int b = 0; b < BBATCH; ++b) part[rc][b][col] = acc[b];
    __syncthreads();

    if (tid < 64) {
        const int b = tid >> 4;
        const int c = tid & 15;
        float4 s4 = make_float4(0.f, 0.f, 0.f, 0.f);
#pragma unroll
        for (int q = 0; q < 16; ++q) {
            float4 p = part[q][b][c];
            s4.x += p.x; s4.y += p.y; s4.z += p.z; s4.w += p.w;
        }
        ((float4*)ws)[(size_t)(b * KEXP + k) * 256 + chunk * 16 + c] = s4;
        float p1 = s4.x + s4.y + s4.z + s4.w;
        float p2 = dot4(s4, s4);
#pragma unroll
        for (int off = 8; off > 0; off >>= 1) {
            p1 += __shfl_xor(p1, off, 64);
            p2 += __shfl_xor(p2, off, 64);
        }
        if (c == 0) {
            ws[WS_PSTAT + ((b * KEXP + k) * 16 + chunk) * 2 + 0] = p1;
            ws[WS_PSTAT + ((b * KEXP + k) * 16 + chunk) * 2 + 1] = p2;
        }
    }
}

// ---- K3: finalize LN stats, build bvec in LDS, comp matvec.
// bvec_d = g_d*(sum_k alpha_k*s[k,d] - C_b) + b_d*wsum_b,
// alpha_k = w_k*rsqrt(var_k+eps), C_b = sum_k alpha_k*mu_k.
__global__ __launch_bounds__(256) void k_comp2(const float* __restrict__ ws,
                                               const float* __restrict__ ln_g,
                                               const float* __restrict__ ln_b,
                                               const float* __restrict__ comp_w,
                                               const float* __restrict__ comp_b,
                                               float* __restrict__ out) {
    const int tid = threadIdx.x;
    const int lane = tid & 63;
    const int wv = tid >> 6;

    __shared__ float alpha_sh[BBATCH][KEXP];
    __shared__ float amu_sh[BBATCH][KEXP];
    __shared__ float Cb[BBATCH], Wsum[BBATCH];
    __shared__ float4 bv[BBATCH][256];

    if (tid < BBATCH * KEXP) {
        const int b = tid / KEXP;
        const int k = tid % KEXP;
        float s1 = 0.f, s2 = 0.f;
#pragma unroll
        for (int c = 0; c < 16; ++c) {
            s1 += ws[WS_PSTAT + ((b * KEXP + k) * 16 + c) * 2 + 0];
            s2 += ws[WS_PSTAT + ((b * KEXP + k) * 16 + c) * 2 + 1];
        }
        const float mu = s1 * (1.f / (float)DDIM);
        const float var = s2 * (1.f / (float)DDIM) - mu * mu;
        const float rs = rsqrtf(var + LN_EPS_C);
        const float w = ws[WS_W + b * 8 + k];
        alpha_sh[b][k] = w * rs;
        amu_sh[b][k] = w * rs * mu;
    }
    __syncthreads();
    if (tid < BBATCH) {
        float c = 0.f;
#pragma unroll
        for (int k = 0; k < KEXP; ++k) c += amu_sh[tid][k];
        Cb[tid] = c;
        Wsum[tid] = ws[WS_W + tid * 8 + 7];
    }
    __syncthreads();

    {
        const float4 g4 = ((const float4*)ln_g)[tid];
        const float4 b4 = ((const float4*)ln_b)[tid];
        const float4* s4p = (const float4*)ws;   // WS_S == 0
#pragma unroll
        for (int b = 0; b < BBATCH; ++b) {
            float4 s = make_float4(0.f, 0.f, 0.f, 0.f);
#pragma unroll
            for (int k = 0; k < KEXP; ++k) {
                const float a = alpha_sh[b][k];
                float4 v = s4p[(size_t)(b * KEXP + k) * 256 + tid];
                s.x = fmaf(a, v.x, s.x);
                s.y = fmaf(a, v.y, s.y);
                s.z = fmaf(a, v.z, s.z);
                s.w = fmaf(a, v.w, s.w);
            }
            const float C = Cb[b], wsum = Wsum[b];
            float4 o;
            o.x = g4.x * (s.x - C) + b4.x * wsum;
            o.y = g4.y * (s.y - C) + b4.y * wsum;
            o.z = g4.z * (s.z - C) + b4.z * wsum;
            o.w = g4.w * (s.w - C) + b4.w * wsum;
            bv[b][tid] = o;
        }
    }
    __syncthreads();

    const int e = blockIdx.x * 4 + wv;
    const float4* cw4 = (const float4*)(comp_w + (size_t)e * DDIM);
    float acc[BBATCH] = {0.f, 0.f, 0.f, 0.f};
#pragma unroll
    for (int j = 0; j < 4; ++j) {
        float4 c = cw4[j * 64 + lane];
#pragma unroll
        for (int b = 0; b < BBATCH; ++b) acc[b] += dot4(c, bv[b][j * 64 + lane]);
    }
#pragma unroll
    for (int b = 0; b < BBATCH; ++b)
#pragma unroll
        for (int off = 32; off > 0; off >>= 1)
            acc[b] += __shfl_xor(acc[b], off, 64);
    if (lane == 0) {
        const float cb = comp_b[e];
#pragma unroll
        for (int b = 0; b < BBATCH; ++b)
            out[b * DDIM + e] = acc[b] + cb;
    }
}

extern "C" void kernel_launch(void* const* d_in, const int* in_sizes, int n_in,
                              void* d_out, int out_size, void* d_ws, size_t ws_size,
                              hipStream_t stream) {
    const float* h      = (const float*)d_in[0];
    const float* gate_w = (const float*)d_in[1];
    const float* gate_b = (const float*)d_in[2];
    const float* U_w    = (const float*)d_in[3];
    const float* V      = (const float*)d_in[4];
    const float* ln_g   = (const float*)d_in[5];
    const float* ln_b   = (const float*)d_in[6];
    const float* comp_w = (const float*)d_in[7];
    const float* comp_b = (const float*)d_in[8];

    float* out = (float*)d_out;                 // b: 4*1024 floats
    float* G   = out + BBATCH * DDIM;           // G: 4*2048*7 floats
    float* ws  = (float*)d_ws;

    k_gate_plus<<<548, 256, 0, stream>>>(h, gate_w, gate_b, U_w, G, ws);
    k_sv<<<KEXP * 16, 256, 0, stream>>>(V, ws);
    k_comp2<<<256, 256, 0, stream>>>(ws, ln_g, ln_b, comp_w, comp_b, out);
}